// Round 8
// baseline (671.746 us; speedup 1.0000x reference)
//
#include <hip/hip_runtime.h>

#define DEV __device__ __forceinline__

// ---- quantizer helpers (exact, round-half-even matches jnp.round) ----
DEV float qwt(float w) {
    float y = fminf(fmaxf(w, -1.0f), 0.875f);
    return rintf(y * 8.0f) * 0.125f;
}
DEV int qw8i(float w) {                       // weight -> int in [-8,7]
    float y = fminf(fmaxf(w, -1.0f), 0.875f);
    return (int)rintf(y * 8.0f);
}
DEV int q8i(float x, float a, float b) {      // act -> int in [-8,7]
    float y = fmaf(x, a, b);
    y = fminf(fmaxf(y, -1.0f), 0.875f);
    return (int)rintf(y * 8.0f);
}
DEV float qact(float x, float a, float b) {
    float y = fmaf(x, a, b);
    y = fminf(fmaxf(y, -1.0f), 0.875f);
    return rintf(y * 8.0f) * 0.125f;
}

DEV int dot4(int a, int b, int c) {
#if __has_builtin(__builtin_amdgcn_sdot4)
    return __builtin_amdgcn_sdot4(a, b, c, false);
#else
    c += (int)(signed char)(a)       * (int)(signed char)(b);
    c += (int)(signed char)(a >> 8)  * (int)(signed char)(b >> 8);
    c += (int)(signed char)(a >> 16) * (int)(signed char)(b >> 16);
    c += (int)(signed char)(a >> 24) * (int)(signed char)(b >> 24);
    return c;
#endif
}
DEV unsigned alignpair(unsigned hi, unsigned lo, int bits) {
#if __has_builtin(__builtin_amdgcn_alignbit)
    return __builtin_amdgcn_alignbit(hi, lo, bits);
#else
    return bits ? ((lo >> bits) | (hi << (32 - bits))) : lo;
#endif
}

// pack float OIHW weights -> int8x4 dwords (value*8), zero-padded past K
DEV void pack_layer(const float* w, int* o, int CIN, int COUT, int K, int t) {
    int KW = (K + 3) / 4;
    for (int i = t; i < COUT * CIN * KW; i += 256) {
        int j = i % KW, cc = i / KW;
        unsigned r = 0;
        for (int u = 0; u < 4; u++) {
            int k = 4 * j + u;
            int b = (k < K) ? (qw8i(w[cc * K + k]) & 0xff) : 0;
            r |= (unsigned)b << (8 * u);
        }
        o[i] = (int)r;
    }
}

// ---------------------------------------------------------------------------
// In-prologue BN bridge: deterministic fp64 reduction of producer's fp32
// partials (transposed layout [slot][Gin], slot 2c = sum_c, 2c+1 = sumsq_c).
// 4 lanes per slot, fixed tree -> identical bits in every block.
// ---------------------------------------------------------------------------
template<int C>
DEV void bridge(const float* __restrict__ partialIn, int Gin, double N,
                const float* __restrict__ gprev, const float* __restrict__ bprev,
                float* ts, float* tb, float fold, double* dred)
{
    const int tid = threadIdx.x;
    if (tid < 8 * C) {
        int s = tid >> 2, q = tid & 3;
        double a = 0.0;
        for (int g = q; g < Gin; g += 4)
            a += (double)partialIn[(size_t)s * Gin + g];
        dred[tid] = a;
    }
    __syncthreads();
    if (tid < C) {
        double S = dred[8 * tid]     + dred[8 * tid + 1] + dred[8 * tid + 2] + dred[8 * tid + 3];
        double Q = dred[8 * tid + 4] + dred[8 * tid + 5] + dred[8 * tid + 6] + dred[8 * tid + 7];
        double mean = S / N;
        double var  = Q / N - mean * mean;
        double inv  = 1.0 / sqrt(var + 1e-5);
        double sc   = (double)gprev[tid] * inv;
        ts[tid] = (float)sc * fold;
        tb[tid] = (float)((double)bprev[tid] - mean * sc);
    }
    __syncthreads();
}

// ---------------------------------------------------------------------------
// int8/dot4 1-D strided conv (stride 2, VALID). Round-6 compute core.
// !IN_FLOAT: prologue bridge from producer partials. IN_FLOAT (conv1):
// packs own weights to LDS; block 0 packs wp2..wp5 to global.
// Stats: round-6 fp32 path, stored transposed [slot][grid].
// ---------------------------------------------------------------------------
template<int CIN,int COUT,int K,int LINP,int LOUT,int LOUTP,int P,int R,bool IN_FLOAT,int LIN=0>
__global__ __launch_bounds__(256) void conv_k(
    const void* __restrict__ in_, const int* __restrict__ wqi,
    const float* __restrict__ partialIn, int Gin,
    const float* __restrict__ gprev, const float* __restrict__ bprev, double Nprev,
    short* __restrict__ out, float* __restrict__ partialOut, int B,
    const float* __restrict__ wown,
    const float* __restrict__ pw2, const float* __restrict__ pw3,
    const float* __restrict__ pw4, const float* __restrict__ pw5,
    int* __restrict__ owp2, int* __restrict__ owp3,
    int* __restrict__ owp4, int* __restrict__ owp5)
{
    constexpr int KW   = (K + 3) / 4;
    constexpr int NE   = P + 2 * KW - 1;
    constexpr int ND   = (2 * (NE - 1) + 3) / 4 + 2;
    constexpr int LO_P = (LOUT + P - 1) / P;
    constexpr int GROUPS = R * LO_P;

    __shared__ __align__(16) signed char smem[R * CIN * LINP + 32];
    __shared__ float ts[CIN], tb[CIN];
    __shared__ float red[4][2 * COUT];
    __shared__ double dred[IN_FLOAT ? 1 : 8 * CIN];
    __shared__ int lwq[IN_FLOAT ? (COUT * CIN * KW) : 1];

    const int tid = threadIdx.x;
    const int bid = blockIdx.x;

    if constexpr (IN_FLOAT) {
        for (int i = tid; i < COUT * CIN * KW; i += 256) {
            int j = i % KW, cc = i / KW;
            unsigned rr = 0;
            for (int u = 0; u < 4; u++) {
                int k = 4 * j + u;
                int bv = (k < K) ? (qw8i(wown[cc * K + k]) & 0xff) : 0;
                rr |= (unsigned)bv << (8 * u);
            }
            lwq[i] = (int)rr;
        }
        if (bid == 0) {
            pack_layer(pw2, owp2, 3, 5, 5, tid);
            pack_layer(pw3, owp3, 5, 10, 4, tid);
            pack_layer(pw4, owp4, 10, 20, 4, tid);
            pack_layer(pw5, owp5, 20, 20, 4, tid);
        }
        __syncthreads();
    } else {
        bridge<CIN>(partialIn, Gin, Nprev, gprev, bprev, ts, tb, 0.015625f, dred);
    }

    const int r0   = bid * R;
    const int rcnt = min(R, B - r0);

    // ---- stage: global -> quantized int8 LDS ----
    if constexpr (IN_FLOAT) {
        constexpr int CH = LIN / 2;
        const float2* gp = (const float2*)in_;
        for (int c = tid; c < rcnt * CH; c += 256) {
            int r = c / CH, rem = c - r * CH;
            float2 v = gp[(size_t)(r0 + r) * CH + rem];
            int b0 = q8i(v.x, 1.f, 0.f) & 0xff;
            int b1 = q8i(v.y, 1.f, 0.f) & 0xff;
            *(unsigned short*)(smem + r * LINP + rem * 2) =
                (unsigned short)(b0 | (b1 << 8));
        }
    } else {
        constexpr int CH  = CIN * LINP / 8;
        constexpr int CHC = LINP / 8;
        const int4* gp = (const int4*)((const short*)in_ + (size_t)r0 * CIN * LINP);
        for (int c = tid; c < rcnt * CH; c += 256) {
            int rem = c % CH;
            int ci = rem / CHC;
            float a = ts[ci], bo = tb[ci];
            int4 v = gp[c];
            int vs[4] = { v.x, v.y, v.z, v.w };
            unsigned pk[2];
#pragma unroll
            for (int u = 0; u < 2; u++) {
                unsigned pp = 0;
#pragma unroll
                for (int j = 0; j < 2; j++) {
                    int word = vs[u * 2 + j];
                    int b0 = q8i((float)(short)(word & 0xffff), a, bo) & 0xff;
                    int b1 = q8i((float)(short)(word >> 16),    a, bo) & 0xff;
                    pp |= (unsigned)(b0 | (b1 << 8)) << (16 * j);
                }
                pk[u] = pp;
            }
            ((uint2*)smem)[c] = make_uint2(pk[0], pk[1]);
        }
    }
    __syncthreads();

    float tsum[COUT], tsq[COUT];
#pragma unroll
    for (int c = 0; c < COUT; c++) { tsum[c] = 0.f; tsq[c] = 0.f; }

    // ---- compute (round-6 core) ----
#pragma unroll 1
    for (int g = tid; g < GROUPS; g += 256) {
        int r = g / LO_P;
        if (r >= rcnt) continue;
        int l0   = (g - r * LO_P) * P;
        int pact = min(P, LOUT - l0);

        int acc[COUT][P];
#pragma unroll
        for (int co = 0; co < COUT; co++)
#pragma unroll
            for (int p = 0; p < P; p++) acc[co][p] = 0;

        const int ibase = r * CIN * LINP + 2 * l0;
        const int sh    = (P % 2 == 0) ? 0 : (ibase & 3);

        for (int ci = 0; ci < CIN; ci++) {
            const int* sp = (const int*)smem + ((ci * LINP + (ibase & ~3)) >> 2);
            int d[ND];
#pragma unroll
            for (int j = 0; j < ND; j++) d[j] = sp[j];
            int e[NE];
#pragma unroll
            for (int i = 0; i < NE; i++) {
                int off = sh + 2 * i;
                e[i] = (int)alignpair((unsigned)d[off / 4 + 1], (unsigned)d[off / 4], (off & 3) * 8);
            }
#pragma unroll
            for (int co = 0; co < COUT; co++) {
#pragma unroll
                for (int j = 0; j < KW; j++) {
                    int wv;
                    if constexpr (IN_FLOAT) wv = lwq[(co * CIN + ci) * KW + j];
                    else                    wv = wqi[(co * CIN + ci) * KW + j];
#pragma unroll
                    for (int p = 0; p < P; p++)
                        acc[co][p] = dot4(e[p + 2 * j], wv, acc[co][p]);
                }
            }
        }

        const size_t ob = (size_t)(r0 + r) * COUT * LOUTP + l0;
#pragma unroll
        for (int co = 0; co < COUT; co++) {
            if (pact == P) {
                short tmp[P];
#pragma unroll
                for (int p = 0; p < P; p++) {
                    tmp[p] = (short)acc[co][p];
                    float v = (float)acc[co][p] * 0.015625f;
                    tsum[co] += v;
                    tsq[co]   = fmaf(v, v, tsq[co]);
                }
                short* op = &out[ob + (size_t)co * LOUTP];
                if constexpr (P == 1) {
                    op[0] = tmp[0];
                } else if constexpr (P == 2) {
                    *(short2*)op = make_short2(tmp[0], tmp[1]);
                } else if constexpr (P == 4) {
                    *(short4*)op = make_short4(tmp[0], tmp[1], tmp[2], tmp[3]);
                } else if constexpr (P == 8) {
                    *(short4*)op       = make_short4(tmp[0], tmp[1], tmp[2], tmp[3]);
                    *(short4*)(op + 4) = make_short4(tmp[4], tmp[5], tmp[6], tmp[7]);
                }
            } else {
#pragma unroll
                for (int p = 0; p < P; p++) {
                    if (p < pact) {
                        int k = acc[co][p];
                        out[ob + (size_t)co * LOUTP + p] = (short)k;
                        float v = (float)k * 0.015625f;
                        tsum[co] += v;
                        tsq[co]   = fmaf(v, v, tsq[co]);
                    }
                }
            }
        }
    }

    // ---- fp32 stat reduction -> transposed partials ----
    const int lane = tid & 63, wid = tid >> 6;
#pragma unroll
    for (int co = 0; co < COUT; co++) {
        float s = tsum[co], q = tsq[co];
        for (int off = 32; off > 0; off >>= 1) {
            s += __shfl_down(s, off, 64);
            q += __shfl_down(q, off, 64);
        }
        if (lane == 0) { red[wid][2 * co] = s; red[wid][2 * co + 1] = q; }
    }
    __syncthreads();
    if (tid < 2 * COUT) {
        float v = red[0][tid] + red[1][tid] + red[2][tid] + red[3][tid];
        partialOut[(size_t)tid * gridDim.x + bid] = v;
    }
}

// ---------------------------------------------------------------------------
// FC1: (B,740)x(10,740)^T, one wave per row (grid 2048). Prologue bridge
// from conv5 partials; stats out transposed fp32 partials.
// ---------------------------------------------------------------------------
__global__ __launch_bounds__(256) void fc1_k(
    const short* __restrict__ y5, const float* __restrict__ fw1,
    const float* __restrict__ partialIn, int Gin,
    const float* __restrict__ g5, const float* __restrict__ b5,
    float* __restrict__ z1, float* __restrict__ partialOut, int B)
{
    __shared__ float wq[7400];
    __shared__ float ts[20], tb[20];
    __shared__ float red[4][20];
    __shared__ double dred[160];

    const int tid = threadIdx.x;
    const int bid = blockIdx.x;

    for (int i = tid; i < 7400; i += 256) wq[i] = qwt(fw1[i]);
    bridge<20>(partialIn, Gin, 8192.0 * 37.0, g5, b5, ts, tb, 1.0f, dred);

    const int lane = tid & 63, wid = tid >> 6;
    const int r = bid * 4 + wid;             // 2048 x 4 waves = 8192 rows
    const short* xr = y5 + (size_t)r * 800;  // 20ch x 40 padded
    float acc[10];
#pragma unroll
    for (int j = 0; j < 10; j++) acc[j] = 0.f;
#pragma unroll 1
    for (int f = lane; f < 740; f += 64) {
        int c = f / 37, pos = f - c * 37;
        float x = qact((float)xr[c * 40 + pos] * 0.015625f, ts[c], tb[c]);
#pragma unroll
        for (int j = 0; j < 10; j++) acc[j] = fmaf(x, wq[j * 740 + f], acc[j]);
    }
    float tsum[10], tsq[10];
#pragma unroll
    for (int j = 0; j < 10; j++) {
        float v = acc[j];
        for (int off = 1; off < 64; off <<= 1) v += __shfl_xor(v, off, 64);
        if (lane == j) z1[(size_t)r * 10 + j] = v;
        tsum[j] = v; tsq[j] = v * v;
    }
    if (lane == 0) {
#pragma unroll
        for (int j = 0; j < 10; j++) { red[wid][2 * j] = tsum[j]; red[wid][2 * j + 1] = tsq[j]; }
    }
    __syncthreads();
    if (tid < 20) {
        float v = red[0][tid] + red[1][tid] + red[2][tid] + red[3][tid];
        partialOut[(size_t)tid * gridDim.x + bid] = v;
    }
}

// ---------------------------------------------------------------------------
// FC2 fused single-block: bridge from fc1 partials -> ts7; z2 (LDS) +
// stats -> tr8; final BN apply -> out.
// ---------------------------------------------------------------------------
__global__ __launch_bounds__(256) void fc2_fused_k(
    const float* __restrict__ z1, const float* __restrict__ fw2,
    const float* __restrict__ partialIn, int Gin,
    const float* __restrict__ g6, const float* __restrict__ b6,
    const float* __restrict__ g7, const float* __restrict__ b7,
    float* __restrict__ outp, int B)
{
    __shared__ float zbuf[16384];
    __shared__ float ts7[10], tb7[10], wq2[20];
    __shared__ double dred[80];
    __shared__ float fr[4][4];
    __shared__ float tr8[4];

    const int tid = threadIdx.x;
    const int lane = tid & 63, wid = tid >> 6;

    if (tid < 20) wq2[tid] = qwt(fw2[tid]);
    bridge<10>(partialIn, Gin, 8192.0, g6, b6, ts7, tb7, 1.0f, dred);

    float s0 = 0.f, q0 = 0.f, s1 = 0.f, q1 = 0.f;
#pragma unroll 1
    for (int r = tid; r < B; r += 256) {
        float a0 = 0.f, a1 = 0.f;
#pragma unroll
        for (int i = 0; i < 10; i++) {
            float x = qact(z1[(size_t)r * 10 + i], ts7[i], tb7[i]);
            a0 = fmaf(x, wq2[i], a0);
            a1 = fmaf(x, wq2[10 + i], a1);
        }
        zbuf[r * 2]     = a0;
        zbuf[r * 2 + 1] = a1;
        s0 += a0; q0 = fmaf(a0, a0, q0);
        s1 += a1; q1 = fmaf(a1, a1, q1);
    }
    for (int off = 32; off > 0; off >>= 1) {
        s0 += __shfl_down(s0, off, 64); q0 += __shfl_down(q0, off, 64);
        s1 += __shfl_down(s1, off, 64); q1 += __shfl_down(q1, off, 64);
    }
    if (lane == 0) { fr[wid][0] = s0; fr[wid][1] = q0; fr[wid][2] = s1; fr[wid][3] = q1; }
    __syncthreads();
    if (tid < 2) {
        double S = 0.0, Q = 0.0;
        for (int w = 0; w < 4; w++) { S += (double)fr[w][2 * tid]; Q += (double)fr[w][2 * tid + 1]; }
        double N = (double)B;
        double mean = S / N;
        double var  = Q / N - mean * mean;
        double inv  = 1.0 / sqrt(var + 1e-5);
        double sc   = (double)g7[tid] * inv;
        tr8[tid]     = (float)sc;
        tr8[2 + tid] = (float)((double)b7[tid] - mean * sc);
    }
    __syncthreads();
    for (int i = tid; i < 2 * B; i += 256) {
        int c = i & 1;
        outp[i] = fmaf(zbuf[i], tr8[c], tr8[2 + c]);
    }
}

// ---------------------------------------------------------------------------
extern "C" void kernel_launch(void* const* d_in, const int* in_sizes, int n_in,
                              void* d_out, int out_size, void* d_ws, size_t ws_size,
                              hipStream_t stream)
{
    const float* x   = (const float*)d_in[0];
    const float* w1  = (const float*)d_in[1];
    const float* w2  = (const float*)d_in[2];
    const float* w3  = (const float*)d_in[3];
    const float* w4  = (const float*)d_in[4];
    const float* w5  = (const float*)d_in[5];
    const float* fw1 = (const float*)d_in[6];
    const float* fw2 = (const float*)d_in[7];
    const float *g[7], *bb[7];
    for (int i = 0; i < 7; i++) { g[i] = (const float*)d_in[8 + 2 * i]; bb[i] = (const float*)d_in[9 + 2 * i]; }

    char* ws = (char*)d_ws;
    size_t off = 0;
    auto alloc = [&](size_t bytes) -> void* {
        void* q = ws + off;
        off += (bytes + 255) & ~(size_t)255;
        return q;
    };
    short* y1 = (short*)alloc((size_t)8192 * 3 * 624 * 2);
    short* y2 = (short*)alloc((size_t)8192 * 5 * 312 * 2);
    short* y3 = (short*)alloc((size_t)8192 * 10 * 160 * 2);
    short* y4 = (short*)alloc((size_t)8192 * 20 * 80 * 2);
    short* y5 = (short*)alloc((size_t)8192 * 20 * 40 * 2);
    float* z1 = (float*)alloc((size_t)81920 * 4);
    int*   wp2 = (int*)alloc(256);  int* wp3 = (int*)alloc(256);
    int*   wp4 = (int*)alloc(1024); int* wp5 = (int*)alloc(2048);
    // fp32 partials, transposed [slot][grid]
    float* p1 = (float*)alloc((size_t)6  * 2731 * 4);
    float* p2 = (float*)alloc((size_t)10 * 2048 * 4);
    float* p3 = (float*)alloc((size_t)20 * 2048 * 4);
    float* p4 = (float*)alloc((size_t)40 * 2048 * 4);
    float* p5 = (float*)alloc((size_t)40 * 1024 * 4);
    float* p6 = (float*)alloc((size_t)20 * 2048 * 4);

    const int B = 8192;

    // conv1: (B,1,1250) f32 -> (B,3,624p) ; P=8, R=3, grid 2731 (+pack wp2..5)
    conv_k<1, 3, 6, 1252, 623, 624, 8, 3, true, 1250><<<2731, 256, 0, stream>>>(
        x, nullptr, nullptr, 0, nullptr, nullptr, 0.0, y1, p1, B,
        w1, w2, w3, w4, w5, wp2, wp3, wp4, wp5);
    // conv2: P=4, R=4, grid 2048 (bridge BN1 from p1)
    conv_k<3, 5, 5, 624, 310, 312, 4, 4, false><<<2048, 256, 0, stream>>>(
        y1, wp2, p1, 2731, g[0], bb[0], 8192.0 * 623.0, y2, p2, B,
        nullptr, nullptr, nullptr, nullptr, nullptr, nullptr, nullptr, nullptr, nullptr);
    // conv3: P=2, R=4, grid 2048
    conv_k<5, 10, 4, 312, 154, 160, 2, 4, false><<<2048, 256, 0, stream>>>(
        y2, wp3, p2, 2048, g[1], bb[1], 8192.0 * 310.0, y3, p3, B,
        nullptr, nullptr, nullptr, nullptr, nullptr, nullptr, nullptr, nullptr, nullptr);
    // conv4: P=1, R=4, grid 2048
    conv_k<10, 20, 4, 160, 76, 80, 1, 4, false><<<2048, 256, 0, stream>>>(
        y3, wp4, p3, 2048, g[2], bb[2], 8192.0 * 154.0, y4, p4, B,
        nullptr, nullptr, nullptr, nullptr, nullptr, nullptr, nullptr, nullptr, nullptr);
    // conv5: P=1, R=8, grid 1024
    conv_k<20, 20, 4, 80, 37, 40, 1, 8, false><<<1024, 256, 0, stream>>>(
        y4, wp5, p4, 2048, g[3], bb[3], 8192.0 * 76.0, y5, p5, B,
        nullptr, nullptr, nullptr, nullptr, nullptr, nullptr, nullptr, nullptr, nullptr);
    // fc1: grid 2048, one row per wave (bridge BN5 from p5)
    fc1_k<<<2048, 256, 0, stream>>>(y5, fw1, p5, 1024, g[4], bb[4], z1, p6, B);
    // fc2 + bridge(fc1) + stats + apply, single block
    fc2_fused_k<<<1, 256, 0, stream>>>(z1, fw2, p6, 2048, g[5], bb[5], g[6], bb[6],
                                       (float*)d_out, B);
}

// Round 9
// 601.699 us; speedup vs baseline: 1.1164x; 1.1164x over previous
//
#include <hip/hip_runtime.h>

#define DEV __device__ __forceinline__

// ---- quantizer helpers (exact, round-half-even matches jnp.round) ----
DEV float qwt(float w) {
    float y = fminf(fmaxf(w, -1.0f), 0.875f);
    return rintf(y * 8.0f) * 0.125f;
}
DEV int qw8i(float w) {                       // weight -> int in [-8,7]
    float y = fminf(fmaxf(w, -1.0f), 0.875f);
    return (int)rintf(y * 8.0f);
}
DEV int q8i(float x, float a, float b) {      // act -> int in [-8,7]
    float y = fmaf(x, a, b);
    y = fminf(fmaxf(y, -1.0f), 0.875f);
    return (int)rintf(y * 8.0f);
}
DEV float qact(float x, float a, float b) {
    float y = fmaf(x, a, b);
    y = fminf(fmaxf(y, -1.0f), 0.875f);
    return rintf(y * 8.0f) * 0.125f;
}

DEV int dot4(int a, int b, int c) {
#if __has_builtin(__builtin_amdgcn_sdot4)
    return __builtin_amdgcn_sdot4(a, b, c, false);
#else
    c += (int)(signed char)(a)       * (int)(signed char)(b);
    c += (int)(signed char)(a >> 8)  * (int)(signed char)(b >> 8);
    c += (int)(signed char)(a >> 16) * (int)(signed char)(b >> 16);
    c += (int)(signed char)(a >> 24) * (int)(signed char)(b >> 24);
    return c;
#endif
}
DEV unsigned alignpair(unsigned hi, unsigned lo, int bits) {
#if __has_builtin(__builtin_amdgcn_alignbit)
    return __builtin_amdgcn_alignbit(hi, lo, bits);
#else
    return bits ? ((lo >> bits) | (hi << (32 - bits))) : lo;
#endif
}

// pack float OIHW weights -> int8x4 dwords (value*8), zero-padded past K
DEV void pack_layer(const float* w, int* o, int CIN, int COUT, int K, int t) {
    int KW = (K + 3) / 4;
    for (int i = t; i < COUT * CIN * KW; i += 256) {
        int j = i % KW, cc = i / KW;
        unsigned r = 0;
        for (int u = 0; u < 4; u++) {
            int k = 4 * j + u;
            int b = (k < K) ? (qw8i(w[cc * K + k]) & 0xff) : 0;
            r |= (unsigned)b << (8 * u);
        }
        o[i] = (int)r;
    }
}

// ---------------------------------------------------------------------------
// In-prologue BN bridge v2: ALL 256 threads reduce producer's fp32 partials
// (layout [slot][Gin]) -- coalesced 256-wide loads, fp64 per-thread partials,
// fixed-tree wave shfl reduce, one barrier, 4-way final sum. Deterministic:
// every block runs the identical tree on identical data.
// ---------------------------------------------------------------------------
template<int C>
DEV void bridge2(const float* __restrict__ pin, int Gin, double N,
                 const float* __restrict__ gprev, const float* __restrict__ bprev,
                 float* ts, float* tb, float fold, double (*wred)[4])
{
    const int tid = threadIdx.x;
    const int lane = tid & 63, wid = tid >> 6;
#pragma unroll 1
    for (int s = 0; s < 2 * C; s++) {
        double a = 0.0;
        for (int g = tid; g < Gin; g += 256)
            a += (double)pin[(size_t)s * Gin + g];
        for (int off = 32; off > 0; off >>= 1)
            a += __shfl_down(a, off, 64);
        if (lane == 0) wred[s][wid] = a;
    }
    __syncthreads();
    if (tid < C) {
        double S = (wred[2 * tid][0]     + wred[2 * tid][1])     + (wred[2 * tid][2]     + wred[2 * tid][3]);
        double Q = (wred[2 * tid + 1][0] + wred[2 * tid + 1][1]) + (wred[2 * tid + 1][2] + wred[2 * tid + 1][3]);
        double mean = S / N;
        double var  = Q / N - mean * mean;
        double inv  = 1.0 / sqrt(var + 1e-5);
        double sc   = (double)gprev[tid] * inv;
        ts[tid] = (float)sc * fold;
        tb[tid] = (float)((double)bprev[tid] - mean * sc);
    }
    __syncthreads();
}

// ---------------------------------------------------------------------------
// int8/dot4 1-D strided conv (stride 2, VALID). Round-6 compute core.
// !IN_FLOAT: prologue bridge2 from producer partials. IN_FLOAT (conv1):
// packs own weights to LDS; block 0 packs wp2..wp5 to global.
// Stats: fp32 path, stored transposed [slot][grid].
// ---------------------------------------------------------------------------
template<int CIN,int COUT,int K,int LINP,int LOUT,int LOUTP,int P,int R,bool IN_FLOAT,int LIN=0>
__global__ __launch_bounds__(256) void conv_k(
    const void* __restrict__ in_, const int* __restrict__ wqi,
    const float* __restrict__ partialIn, int Gin,
    const float* __restrict__ gprev, const float* __restrict__ bprev, double Nprev,
    short* __restrict__ out, float* __restrict__ partialOut, int B,
    const float* __restrict__ wown,
    const float* __restrict__ pw2, const float* __restrict__ pw3,
    const float* __restrict__ pw4, const float* __restrict__ pw5,
    int* __restrict__ owp2, int* __restrict__ owp3,
    int* __restrict__ owp4, int* __restrict__ owp5)
{
    constexpr int KW   = (K + 3) / 4;
    constexpr int NE   = P + 2 * KW - 1;
    constexpr int ND   = (2 * (NE - 1) + 3) / 4 + 2;
    constexpr int LO_P = (LOUT + P - 1) / P;
    constexpr int GROUPS = R * LO_P;

    __shared__ __align__(16) signed char smem[R * CIN * LINP + 32];
    __shared__ float ts[CIN], tb[CIN];
    __shared__ float red[4][2 * COUT];
    __shared__ double wred[IN_FLOAT ? 1 : 2 * CIN][4];
    __shared__ int lwq[IN_FLOAT ? (COUT * CIN * KW) : 1];

    const int tid = threadIdx.x;
    const int bid = blockIdx.x;

    if constexpr (IN_FLOAT) {
        for (int i = tid; i < COUT * CIN * KW; i += 256) {
            int j = i % KW, cc = i / KW;
            unsigned rr = 0;
            for (int u = 0; u < 4; u++) {
                int k = 4 * j + u;
                int bv = (k < K) ? (qw8i(wown[cc * K + k]) & 0xff) : 0;
                rr |= (unsigned)bv << (8 * u);
            }
            lwq[i] = (int)rr;
        }
        if (bid == 0) {
            pack_layer(pw2, owp2, 3, 5, 5, tid);
            pack_layer(pw3, owp3, 5, 10, 4, tid);
            pack_layer(pw4, owp4, 10, 20, 4, tid);
            pack_layer(pw5, owp5, 20, 20, 4, tid);
        }
        __syncthreads();
    } else {
        bridge2<CIN>(partialIn, Gin, Nprev, gprev, bprev, ts, tb, 0.015625f, wred);
    }

    const int r0   = bid * R;
    const int rcnt = min(R, B - r0);

    // ---- stage: global -> quantized int8 LDS ----
    if constexpr (IN_FLOAT) {
        constexpr int CH = LIN / 2;
        const float2* gp = (const float2*)in_;
        for (int c = tid; c < rcnt * CH; c += 256) {
            int r = c / CH, rem = c - r * CH;
            float2 v = gp[(size_t)(r0 + r) * CH + rem];
            int b0 = q8i(v.x, 1.f, 0.f) & 0xff;
            int b1 = q8i(v.y, 1.f, 0.f) & 0xff;
            *(unsigned short*)(smem + r * LINP + rem * 2) =
                (unsigned short)(b0 | (b1 << 8));
        }
    } else {
        constexpr int CH  = CIN * LINP / 8;
        constexpr int CHC = LINP / 8;
        const int4* gp = (const int4*)((const short*)in_ + (size_t)r0 * CIN * LINP);
        for (int c = tid; c < rcnt * CH; c += 256) {
            int rem = c % CH;
            int ci = rem / CHC;
            float a = ts[ci], bo = tb[ci];
            int4 v = gp[c];
            int vs[4] = { v.x, v.y, v.z, v.w };
            unsigned pk[2];
#pragma unroll
            for (int u = 0; u < 2; u++) {
                unsigned pp = 0;
#pragma unroll
                for (int j = 0; j < 2; j++) {
                    int word = vs[u * 2 + j];
                    int b0 = q8i((float)(short)(word & 0xffff), a, bo) & 0xff;
                    int b1 = q8i((float)(short)(word >> 16),    a, bo) & 0xff;
                    pp |= (unsigned)(b0 | (b1 << 8)) << (16 * j);
                }
                pk[u] = pp;
            }
            ((uint2*)smem)[c] = make_uint2(pk[0], pk[1]);
        }
    }
    __syncthreads();

    float tsum[COUT], tsq[COUT];
#pragma unroll
    for (int c = 0; c < COUT; c++) { tsum[c] = 0.f; tsq[c] = 0.f; }

    // ---- compute (round-6 core) ----
#pragma unroll 1
    for (int g = tid; g < GROUPS; g += 256) {
        int r = g / LO_P;
        if (r >= rcnt) continue;
        int l0   = (g - r * LO_P) * P;
        int pact = min(P, LOUT - l0);

        int acc[COUT][P];
#pragma unroll
        for (int co = 0; co < COUT; co++)
#pragma unroll
            for (int p = 0; p < P; p++) acc[co][p] = 0;

        const int ibase = r * CIN * LINP + 2 * l0;
        const int sh    = (P % 2 == 0) ? 0 : (ibase & 3);

        for (int ci = 0; ci < CIN; ci++) {
            const int* sp = (const int*)smem + ((ci * LINP + (ibase & ~3)) >> 2);
            int d[ND];
#pragma unroll
            for (int j = 0; j < ND; j++) d[j] = sp[j];
            int e[NE];
#pragma unroll
            for (int i = 0; i < NE; i++) {
                int off = sh + 2 * i;
                e[i] = (int)alignpair((unsigned)d[off / 4 + 1], (unsigned)d[off / 4], (off & 3) * 8);
            }
#pragma unroll
            for (int co = 0; co < COUT; co++) {
#pragma unroll
                for (int j = 0; j < KW; j++) {
                    int wv;
                    if constexpr (IN_FLOAT) wv = lwq[(co * CIN + ci) * KW + j];
                    else                    wv = wqi[(co * CIN + ci) * KW + j];
#pragma unroll
                    for (int p = 0; p < P; p++)
                        acc[co][p] = dot4(e[p + 2 * j], wv, acc[co][p]);
                }
            }
        }

        const size_t ob = (size_t)(r0 + r) * COUT * LOUTP + l0;
#pragma unroll
        for (int co = 0; co < COUT; co++) {
            if (pact == P) {
                short tmp[P];
#pragma unroll
                for (int p = 0; p < P; p++) {
                    tmp[p] = (short)acc[co][p];
                    float v = (float)acc[co][p] * 0.015625f;
                    tsum[co] += v;
                    tsq[co]   = fmaf(v, v, tsq[co]);
                }
                short* op = &out[ob + (size_t)co * LOUTP];
                if constexpr (P == 1) {
                    op[0] = tmp[0];
                } else if constexpr (P == 2) {
                    *(short2*)op = make_short2(tmp[0], tmp[1]);
                } else if constexpr (P == 4) {
                    *(short4*)op = make_short4(tmp[0], tmp[1], tmp[2], tmp[3]);
                } else if constexpr (P == 8) {
                    *(short4*)op       = make_short4(tmp[0], tmp[1], tmp[2], tmp[3]);
                    *(short4*)(op + 4) = make_short4(tmp[4], tmp[5], tmp[6], tmp[7]);
                }
            } else {
#pragma unroll
                for (int p = 0; p < P; p++) {
                    if (p < pact) {
                        int k = acc[co][p];
                        out[ob + (size_t)co * LOUTP + p] = (short)k;
                        float v = (float)k * 0.015625f;
                        tsum[co] += v;
                        tsq[co]   = fmaf(v, v, tsq[co]);
                    }
                }
            }
        }
    }

    // ---- fp32 stat reduction -> transposed partials ----
    const int lane = tid & 63, wid = tid >> 6;
#pragma unroll
    for (int co = 0; co < COUT; co++) {
        float s = tsum[co], q = tsq[co];
        for (int off = 32; off > 0; off >>= 1) {
            s += __shfl_down(s, off, 64);
            q += __shfl_down(q, off, 64);
        }
        if (lane == 0) { red[wid][2 * co] = s; red[wid][2 * co + 1] = q; }
    }
    __syncthreads();
    if (tid < 2 * COUT) {
        float v = red[0][tid] + red[1][tid] + red[2][tid] + red[3][tid];
        partialOut[(size_t)tid * gridDim.x + bid] = v;
    }
}

// ---------------------------------------------------------------------------
// FC1: (B,740)x(10,740)^T, one wave per row (grid 2048). Prologue bridge2
// from conv5 partials; stats out transposed fp32 partials.
// ---------------------------------------------------------------------------
__global__ __launch_bounds__(256) void fc1_k(
    const short* __restrict__ y5, const float* __restrict__ fw1,
    const float* __restrict__ partialIn, int Gin,
    const float* __restrict__ g5, const float* __restrict__ b5,
    float* __restrict__ z1, float* __restrict__ partialOut, int B)
{
    __shared__ float wq[7400];
    __shared__ float ts[20], tb[20];
    __shared__ float red[4][20];
    __shared__ double wred[40][4];

    const int tid = threadIdx.x;
    const int bid = blockIdx.x;

    for (int i = tid; i < 7400; i += 256) wq[i] = qwt(fw1[i]);
    bridge2<20>(partialIn, Gin, 8192.0 * 37.0, g5, b5, ts, tb, 1.0f, wred);

    const int lane = tid & 63, wid = tid >> 6;
    const int r = bid * 4 + wid;             // 2048 x 4 waves = 8192 rows
    const short* xr = y5 + (size_t)r * 800;  // 20ch x 40 padded
    float acc[10];
#pragma unroll
    for (int j = 0; j < 10; j++) acc[j] = 0.f;
#pragma unroll 1
    for (int f = lane; f < 740; f += 64) {
        int c = f / 37, pos = f - c * 37;
        float x = qact((float)xr[c * 40 + pos] * 0.015625f, ts[c], tb[c]);
#pragma unroll
        for (int j = 0; j < 10; j++) acc[j] = fmaf(x, wq[j * 740 + f], acc[j]);
    }
    float tsum[10], tsq[10];
#pragma unroll
    for (int j = 0; j < 10; j++) {
        float v = acc[j];
        for (int off = 1; off < 64; off <<= 1) v += __shfl_xor(v, off, 64);
        if (lane == j) z1[(size_t)r * 10 + j] = v;
        tsum[j] = v; tsq[j] = v * v;
    }
    if (lane == 0) {
#pragma unroll
        for (int j = 0; j < 10; j++) { red[wid][2 * j] = tsum[j]; red[wid][2 * j + 1] = tsq[j]; }
    }
    __syncthreads();
    if (tid < 20) {
        float v = red[0][tid] + red[1][tid] + red[2][tid] + red[3][tid];
        partialOut[(size_t)tid * gridDim.x + bid] = v;
    }
}

// ---------------------------------------------------------------------------
// FC2 fused single-block: bridge2 from fc1 partials -> ts7; z2 (LDS) +
// stats -> tr8; final BN apply -> out.
// ---------------------------------------------------------------------------
__global__ __launch_bounds__(256) void fc2_fused_k(
    const float* __restrict__ z1, const float* __restrict__ fw2,
    const float* __restrict__ partialIn, int Gin,
    const float* __restrict__ g6, const float* __restrict__ b6,
    const float* __restrict__ g7, const float* __restrict__ b7,
    float* __restrict__ outp, int B)
{
    __shared__ float zbuf[16384];
    __shared__ float ts7[10], tb7[10], wq2[20];
    __shared__ double wred[20][4];
    __shared__ float fr[4][4];
    __shared__ float tr8[4];

    const int tid = threadIdx.x;
    const int lane = tid & 63, wid = tid >> 6;

    if (tid < 20) wq2[tid] = qwt(fw2[tid]);
    bridge2<10>(partialIn, Gin, 8192.0, g6, b6, ts7, tb7, 1.0f, wred);

    float s0 = 0.f, q0 = 0.f, s1 = 0.f, q1 = 0.f;
#pragma unroll 1
    for (int r = tid; r < B; r += 256) {
        float a0 = 0.f, a1 = 0.f;
#pragma unroll
        for (int i = 0; i < 10; i++) {
            float x = qact(z1[(size_t)r * 10 + i], ts7[i], tb7[i]);
            a0 = fmaf(x, wq2[i], a0);
            a1 = fmaf(x, wq2[10 + i], a1);
        }
        zbuf[r * 2]     = a0;
        zbuf[r * 2 + 1] = a1;
        s0 += a0; q0 = fmaf(a0, a0, q0);
        s1 += a1; q1 = fmaf(a1, a1, q1);
    }
    for (int off = 32; off > 0; off >>= 1) {
        s0 += __shfl_down(s0, off, 64); q0 += __shfl_down(q0, off, 64);
        s1 += __shfl_down(s1, off, 64); q1 += __shfl_down(q1, off, 64);
    }
    if (lane == 0) { fr[wid][0] = s0; fr[wid][1] = q0; fr[wid][2] = s1; fr[wid][3] = q1; }
    __syncthreads();
    if (tid < 2) {
        double S = 0.0, Q = 0.0;
        for (int w = 0; w < 4; w++) { S += (double)fr[w][2 * tid]; Q += (double)fr[w][2 * tid + 1]; }
        double N = (double)B;
        double mean = S / N;
        double var  = Q / N - mean * mean;
        double inv  = 1.0 / sqrt(var + 1e-5);
        double sc   = (double)g7[tid] * inv;
        tr8[tid]     = (float)sc;
        tr8[2 + tid] = (float)((double)b7[tid] - mean * sc);
    }
    __syncthreads();
    for (int i = tid; i < 2 * B; i += 256) {
        int c = i & 1;
        outp[i] = fmaf(zbuf[i], tr8[c], tr8[2 + c]);
    }
}

// ---------------------------------------------------------------------------
extern "C" void kernel_launch(void* const* d_in, const int* in_sizes, int n_in,
                              void* d_out, int out_size, void* d_ws, size_t ws_size,
                              hipStream_t stream)
{
    const float* x   = (const float*)d_in[0];
    const float* w1  = (const float*)d_in[1];
    const float* w2  = (const float*)d_in[2];
    const float* w3  = (const float*)d_in[3];
    const float* w4  = (const float*)d_in[4];
    const float* w5  = (const float*)d_in[5];
    const float* fw1 = (const float*)d_in[6];
    const float* fw2 = (const float*)d_in[7];
    const float *g[7], *bb[7];
    for (int i = 0; i < 7; i++) { g[i] = (const float*)d_in[8 + 2 * i]; bb[i] = (const float*)d_in[9 + 2 * i]; }

    char* ws = (char*)d_ws;
    size_t off = 0;
    auto alloc = [&](size_t bytes) -> void* {
        void* q = ws + off;
        off += (bytes + 255) & ~(size_t)255;
        return q;
    };
    short* y1 = (short*)alloc((size_t)8192 * 3 * 624 * 2);
    short* y2 = (short*)alloc((size_t)8192 * 5 * 312 * 2);
    short* y3 = (short*)alloc((size_t)8192 * 10 * 160 * 2);
    short* y4 = (short*)alloc((size_t)8192 * 20 * 80 * 2);
    short* y5 = (short*)alloc((size_t)8192 * 20 * 40 * 2);
    float* z1 = (float*)alloc((size_t)81920 * 4);
    int*   wp2 = (int*)alloc(256);  int* wp3 = (int*)alloc(256);
    int*   wp4 = (int*)alloc(1024); int* wp5 = (int*)alloc(2048);
    // fp32 partials, transposed [slot][grid]
    float* p1 = (float*)alloc((size_t)6  * 2731 * 4);
    float* p2 = (float*)alloc((size_t)10 * 2048 * 4);
    float* p3 = (float*)alloc((size_t)20 * 2048 * 4);
    float* p4 = (float*)alloc((size_t)40 * 2048 * 4);
    float* p5 = (float*)alloc((size_t)40 * 1024 * 4);
    float* p6 = (float*)alloc((size_t)20 * 2048 * 4);

    const int B = 8192;

    // conv1: (B,1,1250) f32 -> (B,3,624p) ; P=8, R=3, grid 2731 (+pack wp2..5)
    conv_k<1, 3, 6, 1252, 623, 624, 8, 3, true, 1250><<<2731, 256, 0, stream>>>(
        x, nullptr, nullptr, 0, nullptr, nullptr, 0.0, y1, p1, B,
        w1, w2, w3, w4, w5, wp2, wp3, wp4, wp5);
    // conv2: P=4, R=4, grid 2048 (bridge BN1 from p1)
    conv_k<3, 5, 5, 624, 310, 312, 4, 4, false><<<2048, 256, 0, stream>>>(
        y1, wp2, p1, 2731, g[0], bb[0], 8192.0 * 623.0, y2, p2, B,
        nullptr, nullptr, nullptr, nullptr, nullptr, nullptr, nullptr, nullptr, nullptr);
    // conv3: P=2, R=4, grid 2048
    conv_k<5, 10, 4, 312, 154, 160, 2, 4, false><<<2048, 256, 0, stream>>>(
        y2, wp3, p2, 2048, g[1], bb[1], 8192.0 * 310.0, y3, p3, B,
        nullptr, nullptr, nullptr, nullptr, nullptr, nullptr, nullptr, nullptr, nullptr);
    // conv4: P=1, R=4, grid 2048
    conv_k<10, 20, 4, 160, 76, 80, 1, 4, false><<<2048, 256, 0, stream>>>(
        y3, wp4, p3, 2048, g[2], bb[2], 8192.0 * 154.0, y4, p4, B,
        nullptr, nullptr, nullptr, nullptr, nullptr, nullptr, nullptr, nullptr, nullptr);
    // conv5: P=1, R=8, grid 1024
    conv_k<20, 20, 4, 80, 37, 40, 1, 8, false><<<1024, 256, 0, stream>>>(
        y4, wp5, p4, 2048, g[3], bb[3], 8192.0 * 76.0, y5, p5, B,
        nullptr, nullptr, nullptr, nullptr, nullptr, nullptr, nullptr, nullptr, nullptr);
    // fc1: grid 2048, one row per wave (bridge BN5 from p5)
    fc1_k<<<2048, 256, 0, stream>>>(y5, fw1, p5, 1024, g[4], bb[4], z1, p6, B);
    // fc2 + bridge(fc1) + stats + apply, single block
    fc2_fused_k<<<1, 256, 0, stream>>>(z1, fw2, p6, 2048, g[5], bb[5], g[6], bb[6],
                                       (float*)d_out, B);
}

// Round 11
// 286.559 us; speedup vs baseline: 2.3442x; 2.0997x over previous
//
#include <hip/hip_runtime.h>

#define DEV __device__ __forceinline__

// ---- quantizer helpers (exact, round-half-even matches jnp.round) ----
DEV float qwt(float w) {
    float y = fminf(fmaxf(w, -1.0f), 0.875f);
    return rintf(y * 8.0f) * 0.125f;
}
DEV int qw8i(float w) {                       // weight -> int in [-8,7]
    float y = fminf(fmaxf(w, -1.0f), 0.875f);
    return (int)rintf(y * 8.0f);
}
DEV int q8i(float x, float a, float b) {      // act -> int in [-8,7]
    float y = fmaf(x, a, b);
    y = fminf(fmaxf(y, -1.0f), 0.875f);
    return (int)rintf(y * 8.0f);
}
DEV float qact(float x, float a, float b) {
    float y = fmaf(x, a, b);
    y = fminf(fmaxf(y, -1.0f), 0.875f);
    return rintf(y * 8.0f) * 0.125f;
}

DEV int dot4(int a, int b, int c) {
#if __has_builtin(__builtin_amdgcn_sdot4)
    return __builtin_amdgcn_sdot4(a, b, c, false);
#else
    c += (int)(signed char)(a)       * (int)(signed char)(b);
    c += (int)(signed char)(a >> 8)  * (int)(signed char)(b >> 8);
    c += (int)(signed char)(a >> 16) * (int)(signed char)(b >> 16);
    c += (int)(signed char)(a >> 24) * (int)(signed char)(b >> 24);
    return c;
#endif
}
DEV unsigned alignpair(unsigned hi, unsigned lo, int bits) {
#if __has_builtin(__builtin_amdgcn_alignbit)
    return __builtin_amdgcn_alignbit(hi, lo, bits);
#else
    return bits ? ((lo >> bits) | (hi << (32 - bits))) : lo;
#endif
}

// f64 atomic add (device scope; safe path)
DEV void atomAddF64(double* p, double v) {
    atomicAdd(p, v);
}

// pack float OIHW weights -> int8x4 dwords (value*8), zero-padded past K
DEV void pack_layer(const float* w, int* o, int CIN, int COUT, int K, int t) {
    int KW = (K + 3) / 4;
    for (int i = t; i < COUT * CIN * KW; i += 256) {
        int j = i % KW, cc = i / KW;
        unsigned r = 0;
        for (int u = 0; u < 4; u++) {
            int k = 4 * j + u;
            int b = (k < K) ? (qw8i(w[cc * K + k]) & 0xff) : 0;
            r |= (unsigned)b << (8 * u);
        }
        o[i] = (int)r;
    }
}

// ---------------------------------------------------------------------------
// int8/dot4 1-D strided conv (stride 2, VALID). Round-6 compute core,
// round-6 fp32 stat path. Stats I/O via 8-slot fp64 accumulators:
//   consumer prologue = 16 fp64 loads + fold math in CIN threads (trivial);
//   producer tail     = one f64 atomicAdd per channel per block.
// IN_FLOAT (conv1): packs own weights to LDS; block 0 packs wp2..5 to global.
// ---------------------------------------------------------------------------
template<int CIN,int COUT,int K,int LINP,int LOUT,int LOUTP,int P,int R,bool IN_FLOAT,int LIN=0>
__global__ __launch_bounds__(256) void conv_k(
    const void* __restrict__ in_, const int* __restrict__ wqi,
    const double* __restrict__ statsIn,
    const float* __restrict__ gprev, const float* __restrict__ bprev, double Nprev,
    short* __restrict__ out, double* __restrict__ statsOut, int B,
    const float* __restrict__ wown,
    const float* __restrict__ pw2, const float* __restrict__ pw3,
    const float* __restrict__ pw4, const float* __restrict__ pw5,
    int* __restrict__ owp2, int* __restrict__ owp3,
    int* __restrict__ owp4, int* __restrict__ owp5)
{
    constexpr int KW   = (K + 3) / 4;
    constexpr int NE   = P + 2 * KW - 1;
    constexpr int ND   = (2 * (NE - 1) + 3) / 4 + 2;
    constexpr int LO_P = (LOUT + P - 1) / P;
    constexpr int GROUPS = R * LO_P;

    __shared__ __align__(16) signed char smem[R * CIN * LINP + 32];
    __shared__ float ts[CIN], tb[CIN];
    __shared__ float red[4][2 * COUT];
    __shared__ int lwq[IN_FLOAT ? (COUT * CIN * KW) : 1];

    const int tid = threadIdx.x;
    const int bid = blockIdx.x;

    if constexpr (IN_FLOAT) {
        for (int i = tid; i < COUT * CIN * KW; i += 256) {
            int j = i % KW, cc = i / KW;
            unsigned rr = 0;
            for (int u = 0; u < 4; u++) {
                int k = 4 * j + u;
                int bv = (k < K) ? (qw8i(wown[cc * K + k]) & 0xff) : 0;
                rr |= (unsigned)bv << (8 * u);
            }
            lwq[i] = (int)rr;
        }
        if (bid == 0) {
            pack_layer(pw2, owp2, 3, 5, 5, tid);
            pack_layer(pw3, owp3, 5, 10, 4, tid);
            pack_layer(pw4, owp4, 10, 20, 4, tid);
            pack_layer(pw5, owp5, 20, 20, 4, tid);
        }
    } else {
        // trivial BN bridge: 16 fp64 loads + fold, CIN threads
        if (tid < CIN) {
            double S = 0.0, Q = 0.0;
#pragma unroll
            for (int s = 0; s < 8; s++) {
                S += statsIn[s * (2 * CIN) + 2 * tid];
                Q += statsIn[s * (2 * CIN) + 2 * tid + 1];
            }
            double mean = S / Nprev;
            double var  = Q / Nprev - mean * mean;
            double inv  = 1.0 / sqrt(var + 1e-5);
            double sc   = (double)gprev[tid] * inv;
            ts[tid] = (float)sc * 0.015625f;     // fold /64 of int16 storage
            tb[tid] = (float)((double)bprev[tid] - mean * sc);
        }
    }
    __syncthreads();

    const int r0   = bid * R;
    const int rcnt = min(R, B - r0);

    // ---- stage: global -> quantized int8 LDS ----
    if constexpr (IN_FLOAT) {
        constexpr int CH = LIN / 2;
        const float2* gp = (const float2*)in_;
        for (int c = tid; c < rcnt * CH; c += 256) {
            int r = c / CH, rem = c - r * CH;
            float2 v = gp[(size_t)(r0 + r) * CH + rem];
            int b0 = q8i(v.x, 1.f, 0.f) & 0xff;
            int b1 = q8i(v.y, 1.f, 0.f) & 0xff;
            *(unsigned short*)(smem + r * LINP + rem * 2) =
                (unsigned short)(b0 | (b1 << 8));
        }
    } else {
        constexpr int CH  = CIN * LINP / 8;
        constexpr int CHC = LINP / 8;
        const int4* gp = (const int4*)((const short*)in_ + (size_t)r0 * CIN * LINP);
        for (int c = tid; c < rcnt * CH; c += 256) {
            int rem = c % CH;
            int ci = rem / CHC;
            float a = ts[ci], bo = tb[ci];
            int4 v = gp[c];
            int vs[4] = { v.x, v.y, v.z, v.w };
            unsigned pk[2];
#pragma unroll
            for (int u = 0; u < 2; u++) {
                unsigned pp = 0;
#pragma unroll
                for (int j = 0; j < 2; j++) {
                    int word = vs[u * 2 + j];
                    int b0 = q8i((float)(short)(word & 0xffff), a, bo) & 0xff;
                    int b1 = q8i((float)(short)(word >> 16),    a, bo) & 0xff;
                    pp |= (unsigned)(b0 | (b1 << 8)) << (16 * j);
                }
                pk[u] = pp;
            }
            ((uint2*)smem)[c] = make_uint2(pk[0], pk[1]);
        }
    }
    __syncthreads();

    float tsum[COUT], tsq[COUT];
#pragma unroll
    for (int c = 0; c < COUT; c++) { tsum[c] = 0.f; tsq[c] = 0.f; }

    // ---- compute (round-6 core, verbatim) ----
#pragma unroll 1
    for (int g = tid; g < GROUPS; g += 256) {
        int r = g / LO_P;
        if (r >= rcnt) continue;
        int l0   = (g - r * LO_P) * P;
        int pact = min(P, LOUT - l0);

        int acc[COUT][P];
#pragma unroll
        for (int co = 0; co < COUT; co++)
#pragma unroll
            for (int p = 0; p < P; p++) acc[co][p] = 0;

        const int ibase = r * CIN * LINP + 2 * l0;
        const int sh    = (P % 2 == 0) ? 0 : (ibase & 3);

        for (int ci = 0; ci < CIN; ci++) {
            const int* sp = (const int*)smem + ((ci * LINP + (ibase & ~3)) >> 2);
            int d[ND];
#pragma unroll
            for (int j = 0; j < ND; j++) d[j] = sp[j];
            int e[NE];
#pragma unroll
            for (int i = 0; i < NE; i++) {
                int off = sh + 2 * i;
                e[i] = (int)alignpair((unsigned)d[off / 4 + 1], (unsigned)d[off / 4], (off & 3) * 8);
            }
#pragma unroll
            for (int co = 0; co < COUT; co++) {
#pragma unroll
                for (int j = 0; j < KW; j++) {
                    int wv;
                    if constexpr (IN_FLOAT) wv = lwq[(co * CIN + ci) * KW + j];
                    else                    wv = wqi[(co * CIN + ci) * KW + j];
#pragma unroll
                    for (int p = 0; p < P; p++)
                        acc[co][p] = dot4(e[p + 2 * j], wv, acc[co][p]);
                }
            }
        }

        const size_t ob = (size_t)(r0 + r) * COUT * LOUTP + l0;
#pragma unroll
        for (int co = 0; co < COUT; co++) {
            if (pact == P) {
                short tmp[P];
#pragma unroll
                for (int p = 0; p < P; p++) {
                    tmp[p] = (short)acc[co][p];
                    float v = (float)acc[co][p] * 0.015625f;
                    tsum[co] += v;
                    tsq[co]   = fmaf(v, v, tsq[co]);
                }
                short* op = &out[ob + (size_t)co * LOUTP];
                if constexpr (P == 1) {
                    op[0] = tmp[0];
                } else if constexpr (P == 2) {
                    *(short2*)op = make_short2(tmp[0], tmp[1]);
                } else if constexpr (P == 4) {
                    *(short4*)op = make_short4(tmp[0], tmp[1], tmp[2], tmp[3]);
                } else if constexpr (P == 8) {
                    *(short4*)op       = make_short4(tmp[0], tmp[1], tmp[2], tmp[3]);
                    *(short4*)(op + 4) = make_short4(tmp[4], tmp[5], tmp[6], tmp[7]);
                }
            } else {
#pragma unroll
                for (int p = 0; p < P; p++) {
                    if (p < pact) {
                        int k = acc[co][p];
                        out[ob + (size_t)co * LOUTP + p] = (short)k;
                        float v = (float)k * 0.015625f;
                        tsum[co] += v;
                        tsq[co]   = fmaf(v, v, tsq[co]);
                    }
                }
            }
        }
    }

    // ---- round-6 fp32 stat reduction -> one fp64 atomic per channel ----
    const int lane = tid & 63, wid = tid >> 6;
#pragma unroll
    for (int co = 0; co < COUT; co++) {
        float s = tsum[co], q = tsq[co];
        for (int off = 32; off > 0; off >>= 1) {
            s += __shfl_down(s, off, 64);
            q += __shfl_down(q, off, 64);
        }
        if (lane == 0) { red[wid][2 * co] = s; red[wid][2 * co + 1] = q; }
    }
    __syncthreads();
    if (tid < 2 * COUT) {
        float v = red[0][tid] + red[1][tid] + red[2][tid] + red[3][tid];
        atomAddF64(&statsOut[(size_t)(bid & 7) * (2 * COUT) + tid], (double)v);
    }
}

// ---------------------------------------------------------------------------
// FC1: (B,740)x(10,740)^T, one wave per row (grid 2048). Trivial bridge in,
// fp64 slot atomics out.
// ---------------------------------------------------------------------------
__global__ __launch_bounds__(256) void fc1_k(
    const short* __restrict__ y5, const float* __restrict__ fw1,
    const double* __restrict__ statsIn,
    const float* __restrict__ g5, const float* __restrict__ b5,
    float* __restrict__ z1, double* __restrict__ statsOut, int B)
{
    __shared__ float wq[7400];
    __shared__ float ts[20], tb[20];
    __shared__ float red[4][20];

    const int tid = threadIdx.x;
    const int bid = blockIdx.x;

    for (int i = tid; i < 7400; i += 256) wq[i] = qwt(fw1[i]);
    if (tid < 20) {
        double S = 0.0, Q = 0.0;
#pragma unroll
        for (int s = 0; s < 8; s++) {
            S += statsIn[s * 40 + 2 * tid];
            Q += statsIn[s * 40 + 2 * tid + 1];
        }
        double N = 8192.0 * 37.0;
        double mean = S / N;
        double var  = Q / N - mean * mean;
        double inv  = 1.0 / sqrt(var + 1e-5);
        double sc   = (double)g5[tid] * inv;
        ts[tid] = (float)sc;                 // x already carries 1/64
        tb[tid] = (float)((double)b5[tid] - mean * sc);
    }
    __syncthreads();

    const int lane = tid & 63, wid = tid >> 6;
    float tsum[10], tsq[10];
#pragma unroll
    for (int j = 0; j < 10; j++) { tsum[j] = 0.f; tsq[j] = 0.f; }

#pragma unroll 1
    for (int r = bid * 4 + wid; r < B; r += gridDim.x * 4) {
        const short* xr = y5 + (size_t)r * 800;   // 20ch x 40 padded
        float acc[10];
#pragma unroll
        for (int j = 0; j < 10; j++) acc[j] = 0.f;
#pragma unroll 1
        for (int f = lane; f < 740; f += 64) {
            int c = f / 37, pos = f - c * 37;
            float x = qact((float)xr[c * 40 + pos] * 0.015625f, ts[c], tb[c]);
#pragma unroll
            for (int j = 0; j < 10; j++) acc[j] = fmaf(x, wq[j * 740 + f], acc[j]);
        }
#pragma unroll
        for (int j = 0; j < 10; j++) {
            float v = acc[j];
            for (int off = 1; off < 64; off <<= 1) v += __shfl_xor(v, off, 64);
            tsum[j] += v; tsq[j] = fmaf(v, v, tsq[j]);
            if (lane == j) z1[(size_t)r * 10 + j] = v;
        }
    }
    if (lane == 0) {
#pragma unroll
        for (int j = 0; j < 10; j++) { red[wid][2 * j] = tsum[j]; red[wid][2 * j + 1] = tsq[j]; }
    }
    __syncthreads();
    if (tid < 20) {
        float v = red[0][tid] + red[1][tid] + red[2][tid] + red[3][tid];
        atomAddF64(&statsOut[(size_t)(bid & 7) * 20 + tid], (double)v);
    }
}

// ---------------------------------------------------------------------------
// FC2 fused single-block: trivial bridge from fc1 slots -> ts7; z2 (LDS) +
// stats -> tr8; final BN apply -> out.
// ---------------------------------------------------------------------------
__global__ __launch_bounds__(256) void fc2_fused_k(
    const float* __restrict__ z1, const float* __restrict__ fw2,
    const double* __restrict__ statsIn,
    const float* __restrict__ g6, const float* __restrict__ b6,
    const float* __restrict__ g7, const float* __restrict__ b7,
    float* __restrict__ outp, int B)
{
    __shared__ float zbuf[16384];
    __shared__ float ts7[10], tb7[10], wq2[20];
    __shared__ float fr[4][4];
    __shared__ float tr8[4];

    const int tid = threadIdx.x;
    const int lane = tid & 63, wid = tid >> 6;

    if (tid < 20) wq2[tid] = qwt(fw2[tid]);
    if (tid < 10) {
        double S = 0.0, Q = 0.0;
#pragma unroll
        for (int s = 0; s < 8; s++) {
            S += statsIn[s * 20 + 2 * tid];
            Q += statsIn[s * 20 + 2 * tid + 1];
        }
        double N = 8192.0;
        double mean = S / N;
        double var  = Q / N - mean * mean;
        double inv  = 1.0 / sqrt(var + 1e-5);
        double sc   = (double)g6[tid] * inv;
        ts7[tid] = (float)sc;
        tb7[tid] = (float)((double)b6[tid] - mean * sc);
    }
    __syncthreads();

    float s0 = 0.f, q0 = 0.f, s1 = 0.f, q1 = 0.f;
#pragma unroll 1
    for (int r = tid; r < B; r += 256) {
        float a0 = 0.f, a1 = 0.f;
#pragma unroll
        for (int i = 0; i < 10; i++) {
            float x = qact(z1[(size_t)r * 10 + i], ts7[i], tb7[i]);
            a0 = fmaf(x, wq2[i], a0);
            a1 = fmaf(x, wq2[10 + i], a1);
        }
        zbuf[r * 2]     = a0;
        zbuf[r * 2 + 1] = a1;
        s0 += a0; q0 = fmaf(a0, a0, q0);
        s1 += a1; q1 = fmaf(a1, a1, q1);
    }
    for (int off = 32; off > 0; off >>= 1) {
        s0 += __shfl_down(s0, off, 64); q0 += __shfl_down(q0, off, 64);
        s1 += __shfl_down(s1, off, 64); q1 += __shfl_down(q1, off, 64);
    }
    if (lane == 0) { fr[wid][0] = s0; fr[wid][1] = q0; fr[wid][2] = s1; fr[wid][3] = q1; }
    __syncthreads();
    if (tid < 2) {
        double S = 0.0, Q = 0.0;
        for (int w = 0; w < 4; w++) { S += (double)fr[w][2 * tid]; Q += (double)fr[w][2 * tid + 1]; }
        double N = (double)B;
        double mean = S / N;
        double var  = Q / N - mean * mean;
        double inv  = 1.0 / sqrt(var + 1e-5);
        double sc   = (double)g7[tid] * inv;
        tr8[tid]     = (float)sc;
        tr8[2 + tid] = (float)((double)b7[tid] - mean * sc);
    }
    __syncthreads();
    for (int i = tid; i < 2 * B; i += 256) {
        int c = i & 1;
        outp[i] = fmaf(zbuf[i], tr8[c], tr8[2 + c]);
    }
}

// ---------------------------------------------------------------------------
extern "C" void kernel_launch(void* const* d_in, const int* in_sizes, int n_in,
                              void* d_out, int out_size, void* d_ws, size_t ws_size,
                              hipStream_t stream)
{
    const float* x   = (const float*)d_in[0];
    const float* w1  = (const float*)d_in[1];
    const float* w2  = (const float*)d_in[2];
    const float* w3  = (const float*)d_in[3];
    const float* w4  = (const float*)d_in[4];
    const float* w5  = (const float*)d_in[5];
    const float* fw1 = (const float*)d_in[6];
    const float* fw2 = (const float*)d_in[7];
    const float *g[7], *bb[7];
    for (int i = 0; i < 7; i++) { g[i] = (const float*)d_in[8 + 2 * i]; bb[i] = (const float*)d_in[9 + 2 * i]; }

    char* ws = (char*)d_ws;
    size_t off = 0;
    auto alloc = [&](size_t bytes) -> void* {
        void* q = ws + off;
        off += (bytes + 255) & ~(size_t)255;
        return q;
    };
    short* y1 = (short*)alloc((size_t)8192 * 3 * 624 * 2);
    short* y2 = (short*)alloc((size_t)8192 * 5 * 312 * 2);
    short* y3 = (short*)alloc((size_t)8192 * 10 * 160 * 2);
    short* y4 = (short*)alloc((size_t)8192 * 20 * 80 * 2);
    short* y5 = (short*)alloc((size_t)8192 * 20 * 40 * 2);
    float* z1 = (float*)alloc((size_t)81920 * 4);
    int*   wp2 = (int*)alloc(256);  int* wp3 = (int*)alloc(256);
    int*   wp4 = (int*)alloc(1024); int* wp5 = (int*)alloc(2048);
    // fp64 stat slots: 8 rows of 2C per layer, contiguous (1088 doubles)
    double* slots = (double*)alloc((size_t)1088 * 8);
    double* sl1 = slots;              // conv1: 8 x 6
    double* sl2 = sl1 + 8 * 6;        // conv2: 8 x 10
    double* sl3 = sl2 + 8 * 10;       // conv3: 8 x 20
    double* sl4 = sl3 + 8 * 20;       // conv4: 8 x 40
    double* sl5 = sl4 + 8 * 40;       // conv5: 8 x 40
    double* sl6 = sl5 + 8 * 40;       // fc1:   8 x 20

    const int B = 8192;

    hipMemsetAsync(slots, 0, (size_t)1088 * 8, stream);

    // conv1: (B,1,1250) f32 -> (B,3,624p) ; P=8, R=3, grid 2731 (+pack wp2..5)
    conv_k<1, 3, 6, 1252, 623, 624, 8, 3, true, 1250><<<2731, 256, 0, stream>>>(
        x, nullptr, nullptr, nullptr, nullptr, 0.0, y1, sl1, B,
        w1, w2, w3, w4, w5, wp2, wp3, wp4, wp5);
    // conv2: P=4, R=4, grid 2048 (bridge BN1 from sl1)
    conv_k<3, 5, 5, 624, 310, 312, 4, 4, false><<<2048, 256, 0, stream>>>(
        y1, wp2, sl1, g[0], bb[0], 8192.0 * 623.0, y2, sl2, B,
        nullptr, nullptr, nullptr, nullptr, nullptr, nullptr, nullptr, nullptr, nullptr);
    // conv3: P=2, R=4, grid 2048
    conv_k<5, 10, 4, 312, 154, 160, 2, 4, false><<<2048, 256, 0, stream>>>(
        y2, wp3, sl2, g[1], bb[1], 8192.0 * 310.0, y3, sl3, B,
        nullptr, nullptr, nullptr, nullptr, nullptr, nullptr, nullptr, nullptr, nullptr);
    // conv4: P=1, R=4, grid 2048
    conv_k<10, 20, 4, 160, 76, 80, 1, 4, false><<<2048, 256, 0, stream>>>(
        y3, wp4, sl3, g[2], bb[2], 8192.0 * 154.0, y4, sl4, B,
        nullptr, nullptr, nullptr, nullptr, nullptr, nullptr, nullptr, nullptr, nullptr);
    // conv5: P=1, R=8, grid 1024
    conv_k<20, 20, 4, 80, 37, 40, 1, 8, false><<<1024, 256, 0, stream>>>(
        y4, wp5, sl4, g[3], bb[3], 8192.0 * 76.0, y5, sl5, B,
        nullptr, nullptr, nullptr, nullptr, nullptr, nullptr, nullptr, nullptr, nullptr);
    // fc1: grid 2048, one row per wave (bridge BN5 from sl5)
    fc1_k<<<2048, 256, 0, stream>>>(y5, fw1, sl5, g[4], bb[4], z1, sl6, B);
    // fc2 + bridge(fc1) + stats + apply, single block
    fc2_fused_k<<<1, 256, 0, stream>>>(z1, fw2, sl6, g[5], bb[5], g[6], bb[6],
                                       (float*)d_out, B);
}